// Round 7
// baseline (713.161 us; speedup 1.0000x reference)
//
#include <hip/hip_runtime.h>
#include <stdint.h>

// Problem constants: B=8, H=W=64, C=256
#define NB    8
#define NTOK  4096          // H*W tokens per batch
#define TOK   32768         // NB*NTOK
#define CDIM  256
#define BQ    128           // queries per block (flash): 32 per wave-pair
#define BK    64            // keys per LDS tile (flash); split 32/32 across wave halves
#define NT    (NTOK / BK)   // 64 key tiles

#define KPITCH 264          // Ks row pitch in shorts (pad +8, baked into k2 global)
#define VPITCH 68           // Vs row pitch in shorts (pad +4, baked into vt2 global)
#define KTILE_SH (BK * KPITCH)     // 16896 shorts = 33792 B
#define VTILE_SH (CDIM * VPITCH)   // 17408 shorts = 34816 B
#define KCH   33
#define VCH   34
#define TOTCH (KCH + VCH)   // 67 1-KB DMA chunks per tile

typedef __attribute__((ext_vector_type(8))) short bf16x8;   // 8 bf16 = 4 VGPRs
typedef __attribute__((ext_vector_type(4))) float f32x4;    // MFMA C/D frag

#define SSCALE 0.09016844f   // C^-0.5 * log2(e) = 0.0625 * 1.442695

static __device__ __forceinline__ unsigned short f2bf(float f) {
    union { float f; unsigned u; } v; v.f = f;
    unsigned r = v.u + 0x7fffu + ((v.u >> 16) & 1u);   // RNE
    return (unsigned short)(r >> 16);
}

// async global->LDS DMA: 16 B/lane, LDS dest = uniform base + lane*16
static __device__ __forceinline__ void dma16(const unsigned short* g, unsigned short* l) {
    __builtin_amdgcn_global_load_lds(
        (const __attribute__((address_space(1))) unsigned int*)g,
        (__attribute__((address_space(3))) unsigned int*)l,
        16, 0, 0);
}

// ---------------- prep: LayerNorm (blocks 0..8191) + weight transpose -------
__global__ __launch_bounds__(256) void prep_kernel(
        const float* __restrict__ x,
        const float* __restrict__ gamma,
        const float* __restrict__ beta,
        const float* __restrict__ w0, const float* __restrict__ w1,
        const float* __restrict__ w2, const float* __restrict__ w3,
        unsigned short* __restrict__ h_bf,
        unsigned short* __restrict__ wt) {
    int bx = blockIdx.x;
    if (bx >= TOK / 4) {
        // weight transpose + bf16 cast: Wt[d][c] = W[c][d]
        int id = bx - TOK / 4;            // 0..1023
        int m = id >> 8, dd = id & 255;
        const float* src = (m == 0) ? w0 : (m == 1) ? w1 : (m == 2) ? w2 : w3;
        wt[m * (CDIM * CDIM) + dd * CDIM + threadIdx.x] = f2bf(src[threadIdx.x * CDIM + dd]);
        return;
    }
    int w = threadIdx.x >> 6;
    int lane = threadIdx.x & 63;
    int token = bx * 4 + w;
    const float4 xv = ((const float4*)(x + (size_t)token * CDIM))[lane];
    float s = xv.x + xv.y + xv.z + xv.w;
    #pragma unroll
    for (int off = 1; off < 64; off <<= 1) s += __shfl_xor(s, off, 64);
    float mean = s * (1.0f / 256.0f);
    float d0 = xv.x - mean, d1 = xv.y - mean, d2 = xv.z - mean, d3 = xv.w - mean;
    float ss = d0 * d0 + d1 * d1 + d2 * d2 + d3 * d3;
    #pragma unroll
    for (int off = 1; off < 64; off <<= 1) ss += __shfl_xor(ss, off, 64);
    float rstd = rsqrtf(ss * (1.0f / 256.0f) + 1e-5f);
    float4 g = ((const float4*)gamma)[lane];
    float4 b = ((const float4*)beta)[lane];
    ushort4 o;
    o.x = f2bf(d0 * rstd * g.x + b.x);
    o.y = f2bf(d1 * rstd * g.y + b.y);
    o.z = f2bf(d2 * rstd * g.z + b.z);
    o.w = f2bf(d3 * rstd * g.w + b.w);
    ((ushort4*)(h_bf + (size_t)token * CDIM))[lane] = o;
}

// ---------------- fused Q+K+V projection -------------------------------------
// One block = one 64-token key tile, 256 thr (4 waves x 16 tokens). h read
// ONCE; A-frags reused across the 3 weight loops. Q -> plain [t][d] scaled;
// K -> padded tiled k2[tile][row][264]; V -> LDS transpose -> padded tiled
// vt2[tile][d][68]. 34.8 KB LDS -> 4 blocks/CU -> 4 waves/SIMD.
__global__ __launch_bounds__(256) void qkv_kernel(
        const unsigned short* __restrict__ h_bf,
        const unsigned short* __restrict__ wts,
        const float* __restrict__ bq,
        const float* __restrict__ bk,
        const float* __restrict__ bv,
        unsigned short* __restrict__ q_bf,
        unsigned short* __restrict__ k2,
        unsigned short* __restrict__ vt2) {
    __shared__ unsigned short VT[CDIM][VPITCH];   // 34816 B
    int tid = threadIdx.x;
    int w = tid >> 6, lane = tid & 63, quad = lane >> 4, l16 = lane & 15;
    int blk = blockIdx.x;
    int tok_base = blk * 64 + w * 16;

    bf16x8 afr[8];
    #pragma unroll
    for (int kk = 0; kk < 8; ++kk)
        afr[kk] = *(const bf16x8*)(h_bf + (size_t)(tok_base + l16) * CDIM + kk * 32 + quad * 8);

    // ---- Q
    {
        const unsigned short* wq_t = wts;
        #pragma unroll
        for (int nt = 0; nt < 16; ++nt) {
            f32x4 acc = {0.f, 0.f, 0.f, 0.f};
            #pragma unroll
            for (int kk = 0; kk < 8; ++kk) {
                bf16x8 bfr = *(const bf16x8*)(wq_t + (size_t)(nt * 16 + l16) * CDIM + kk * 32 + quad * 8);
                acc = __builtin_amdgcn_mfma_f32_16x16x32_bf16(afr[kk], bfr, acc, 0, 0, 0);
            }
            int d = nt * 16 + l16;
            float bb = bq[d];
            #pragma unroll
            for (int r = 0; r < 4; ++r)
                q_bf[(size_t)(tok_base + quad * 4 + r) * CDIM + d] = f2bf((acc[r] + bb) * SSCALE);
        }
    }
    // ---- K (into padded tile)
    {
        const unsigned short* wk_t = wts + CDIM * CDIM;
        unsigned short* kdst = k2 + (size_t)blk * KTILE_SH;
        int row0 = w * 16 + quad * 4;
        #pragma unroll
        for (int nt = 0; nt < 16; ++nt) {
            f32x4 acc = {0.f, 0.f, 0.f, 0.f};
            #pragma unroll
            for (int kk = 0; kk < 8; ++kk) {
                bf16x8 bfr = *(const bf16x8*)(wk_t + (size_t)(nt * 16 + l16) * CDIM + kk * 32 + quad * 8);
                acc = __builtin_amdgcn_mfma_f32_16x16x32_bf16(afr[kk], bfr, acc, 0, 0, 0);
            }
            int d = nt * 16 + l16;
            float bb = bk[d];
            #pragma unroll
            for (int r = 0; r < 4; ++r)
                kdst[(size_t)(row0 + r) * KPITCH + d] = f2bf(acc[r] + bb);
        }
    }
    // ---- V (transpose through LDS into padded tile)
    {
        const unsigned short* wv_t = wts + 2 * CDIM * CDIM;
        int col0 = w * 16 + quad * 4;
        #pragma unroll
        for (int nt = 0; nt < 16; ++nt) {
            f32x4 acc = {0.f, 0.f, 0.f, 0.f};
            #pragma unroll
            for (int kk = 0; kk < 8; ++kk) {
                bf16x8 bfr = *(const bf16x8*)(wv_t + (size_t)(nt * 16 + l16) * CDIM + kk * 32 + quad * 8);
                acc = __builtin_amdgcn_mfma_f32_16x16x32_bf16(afr[kk], bfr, acc, 0, 0, 0);
            }
            int d = nt * 16 + l16;
            float bb = bv[d];
            #pragma unroll
            for (int r = 0; r < 4; ++r)
                VT[d][col0 + r] = f2bf(acc[r] + bb);
        }
    }
    __syncthreads();
    // flat coalesced copy-out: 2176 uint4 over 256 threads
    const uint4* src = (const uint4*)(&VT[0][0]);
    uint4* dst = (uint4*)(vt2 + (size_t)blk * VTILE_SH);
    #pragma unroll
    for (int i = 0; i < 9; ++i) {
        int idx = i * 256 + tid;
        if (idx < (VTILE_SH / 8)) dst[idx] = src[idx];
    }
}

// ---------------- Flash attention: key-split wave pairs, DMA double-buffer ---
// 8 waves, 512 thr, BQ=128. Wave w owns q-rows (w&3)*32..+32 and key half
// (w>>2) of each 64-key tile. Addresses hoisted: one base VGPR per LDS
// stream, all nt/kk/nt2 offsets are compile-time immediates; DMA pointers
// advance incrementally (no per-tile 64-bit recompute).
#define DMA_TILE(KS, VS)                                                             \
    {                                                                                \
        _Pragma("unroll")                                                            \
        for (int i = 0; i < 8; ++i) {                                                \
            int c = w + i * 8;                                                       \
            if (c < KCH) dma16(gk + c * 512 + lane * 8, &KS[0][0] + c * 512);        \
            else dma16(gv + (c - KCH) * 512 + lane * 8, &VS[0][0] + (c - KCH) * 512);\
        }                                                                            \
        if (w < 3) {                                                                 \
            int c = 64 + w;                                                          \
            dma16(gv + (c - KCH) * 512 + lane * 8, &VS[0][0] + (c - KCH) * 512);     \
        }                                                                            \
        gk += KTILE_SH; gv += VTILE_SH;                                              \
    }

#define COMPUTE_TILE(KS, VS)                                                         \
    {                                                                                \
        const unsigned short* KsF = &KS[0][0] + kbase;                               \
        const unsigned short* VsF = &VS[0][0] + vbase;                               \
        f32x4 sfr[2][2];                                                             \
        _Pragma("unroll")                                                            \
        for (int nt = 0; nt < 2; ++nt) {                                             \
            f32x4 a0 = {0.f, 0.f, 0.f, 0.f};                                         \
            f32x4 a1 = {0.f, 0.f, 0.f, 0.f};                                         \
            _Pragma("unroll")                                                        \
            for (int kk = 0; kk < 8; ++kk) {                                         \
                bf16x8 kb = *(const bf16x8*)(KsF + nt * 16 * KPITCH + kk * 32);      \
                a0 = __builtin_amdgcn_mfma_f32_16x16x32_bf16(qfr[0][kk], kb, a0, 0, 0, 0);      \
                a1 = __builtin_amdgcn_mfma_f32_16x16x32_bf16(qfr[1][kk], kb, a1, 0, 0, 0);      \
            }                                                                        \
            sfr[0][nt] = a0; sfr[1][nt] = a1;                                        \
        }                                                                            \
        _Pragma("unroll")                                                            \
        for (int s = 0; s < 2; ++s)                                                  \
            _Pragma("unroll")                                                        \
            for (int nt = 0; nt < 2; ++nt)                                           \
                _Pragma("unroll")                                                    \
                for (int r = 0; r < 4; ++r) {                                        \
                    float p = exp2f(sfr[s][nt][r]);                                  \
                    lacc[s][r] += p;                                                 \
                    pw[(s * 16 + r) * VPITCH + nt * 16] =                            \
                        (unsigned short)(__float_as_uint(p) >> 16);                  \
                }                                                                    \
        bf16x8 pfr0 = *(const bf16x8*)(pr);                                          \
        bf16x8 pfr1 = *(const bf16x8*)(pr + 16 * VPITCH);                            \
        _Pragma("unroll")                                                            \
        for (int nt2 = 0; nt2 < 16; ++nt2) {                                         \
            bf16x8 vb = *(const bf16x8*)(VsF + nt2 * 16 * VPITCH);                   \
            O[0][nt2] = __builtin_amdgcn_mfma_f32_16x16x32_bf16(pfr0, vb, O[0][nt2], 0, 0, 0);  \
            O[1][nt2] = __builtin_amdgcn_mfma_f32_16x16x32_bf16(pfr1, vb, O[1][nt2], 0, 0, 0);  \
        }                                                                            \
    }

__global__ __launch_bounds__(512, 2) void flash_kernel(
        const unsigned short* __restrict__ q_bf,
        const unsigned short* __restrict__ k2,
        const unsigned short* __restrict__ vt2,
        unsigned short* __restrict__ attn) {
    __shared__ unsigned short Ks0[BK][KPITCH];    // 33792 B
    __shared__ unsigned short Ks1[BK][KPITCH];    // 33792 B
    __shared__ unsigned short Vs0[CDIM][VPITCH];  // 34816 B
    __shared__ unsigned short Vs1[CDIM][VPITCH];  // 34816 B
    __shared__ unsigned short Pl[BQ][VPITCH];     // 17408 B  (total 154.6 KB)

    int tid = threadIdx.x;
    int w = tid >> 6, lane = tid & 63, quad = lane >> 4, l16 = lane & 15;
    int kh = w >> 2;        // key half of each tile
    int wq = w & 3;         // q-row group (shared with wave w^4)
    int bid = blockIdx.x;
    int b = bid & 7;        // XCD swizzle: same batch -> same XCD L2
    int qtile = bid >> 3;
    int qrow = qtile * BQ + wq * 32;
    const size_t bbase = (size_t)b * NTOK * CDIM;

    // hoisted per-wave LDS base offsets (elements)
    const int kbase = (kh * 32 + l16) * KPITCH + quad * 8;
    const int vbase = l16 * VPITCH + kh * 32 + quad * 8;
    unsigned short* pw = &Pl[0][0] + (wq * 32 + quad * 4) * VPITCH + kh * 32 + l16;
    const unsigned short* pr = &Pl[0][0] + (wq * 32 + l16) * VPITCH + kh * 32 + quad * 8;

    // incremental DMA pointers
    const unsigned short* gk = k2 + (size_t)b * NT * KTILE_SH;
    const unsigned short* gv = vt2 + (size_t)b * NT * VTILE_SH;

    bf16x8 qfr[2][8];
    #pragma unroll
    for (int s = 0; s < 2; ++s)
        #pragma unroll
        for (int kk = 0; kk < 8; ++kk)
            qfr[s][kk] = *(const bf16x8*)(q_bf + bbase + (size_t)(qrow + s * 16 + l16) * CDIM + kk * 32 + quad * 8);

    f32x4 O[2][16];
    #pragma unroll
    for (int s = 0; s < 2; ++s)
        #pragma unroll
        for (int i = 0; i < 16; ++i) O[s][i] = (f32x4){0.f, 0.f, 0.f, 0.f};
    float lacc[2][4] = {{0.f, 0.f, 0.f, 0.f}, {0.f, 0.f, 0.f, 0.f}};

    DMA_TILE(Ks0, Vs0);
    __syncthreads();

    for (int kt2 = 0; kt2 < NT; kt2 += 2) {
        DMA_TILE(Ks1, Vs1);
        COMPUTE_TILE(Ks0, Vs0);
        __syncthreads();
        if (kt2 + 2 < NT) DMA_TILE(Ks0, Vs0);
        COMPUTE_TILE(Ks1, Vs1);
        __syncthreads();
    }

    // ---- epilogue: combine wave pairs (key halves) through dead LDS buffers
    float* sO = (wq == 0) ? (float*)&Ks0[0][0] : (wq == 1) ? (float*)&Ks1[0][0]
              : (wq == 2) ? (float*)&Vs0[0][0] : (float*)&Vs1[0][0];
    float* sL = (float*)&Pl[0][0] + wq * 512;    // 2*4*64 floats per pair

    if (kh == 1) {
        #pragma unroll
        for (int s = 0; s < 2; ++s) {
            #pragma unroll
            for (int nt2 = 0; nt2 < 16; ++nt2)
                #pragma unroll
                for (int r = 0; r < 4; ++r)
                    sO[((s * 16 + nt2) * 4 + r) * 64 + lane] = O[s][nt2][r];
            #pragma unroll
            for (int r = 0; r < 4; ++r)
                sL[(s * 4 + r) * 64 + lane] = lacc[s][r];
        }
    }
    __syncthreads();
    if (kh == 0) {
        float linv[2][4];
        #pragma unroll
        for (int s = 0; s < 2; ++s)
            #pragma unroll
            for (int r = 0; r < 4; ++r) {
                float ls = lacc[s][r] + sL[(s * 4 + r) * 64 + lane];
                #pragma unroll
                for (int off = 1; off < 16; off <<= 1)
                    ls += __shfl_xor(ls, off, 64);
                linv[s][r] = 1.0f / ls;
            }
        #pragma unroll
        for (int s = 0; s < 2; ++s)
            #pragma unroll
            for (int nt2 = 0; nt2 < 16; ++nt2) {
                int d = nt2 * 16 + l16;
                #pragma unroll
                for (int r = 0; r < 4; ++r) {
                    float val = (O[s][nt2][r] + sO[((s * 16 + nt2) * 4 + r) * 64 + lane]) * linv[s][r];
                    attn[bbase + (size_t)(qrow + s * 16 + quad * 4 + r) * CDIM + d] = f2bf(val);
                }
            }
    }
}

// ---------------- output projection + bias + residual, fp32 out -------------
__global__ __launch_bounds__(128) void oproj_kernel(
        const unsigned short* __restrict__ attn,
        const unsigned short* __restrict__ wo_t,
        const float* __restrict__ bo,
        const float* __restrict__ x,
        float* __restrict__ out) {
    int w = threadIdx.x >> 6, lane = threadIdx.x & 63;
    int quad = lane >> 4, l16 = lane & 15;
    int tok_base = blockIdx.x * 64 + w * 32;

    bf16x8 afr[2][8];
    #pragma unroll
    for (int s = 0; s < 2; ++s)
        #pragma unroll
        for (int kk = 0; kk < 8; ++kk)
            afr[s][kk] = *(const bf16x8*)(attn + (size_t)(tok_base + s * 16 + l16) * CDIM + kk * 32 + quad * 8);

    #pragma unroll
    for (int nt = 0; nt < 16; ++nt) {
        f32x4 acc0 = {0.f, 0.f, 0.f, 0.f};
        f32x4 acc1 = {0.f, 0.f, 0.f, 0.f};
        #pragma unroll
        for (int kk = 0; kk < 8; ++kk) {
            bf16x8 bfr = *(const bf16x8*)(wo_t + (size_t)(nt * 16 + l16) * CDIM + kk * 32 + quad * 8);
            acc0 = __builtin_amdgcn_mfma_f32_16x16x32_bf16(afr[0][kk], bfr, acc0, 0, 0, 0);
            acc1 = __builtin_amdgcn_mfma_f32_16x16x32_bf16(afr[1][kk], bfr, acc1, 0, 0, 0);
        }
        int d = nt * 16 + l16;
        float bb = bo[d];
        #pragma unroll
        for (int r = 0; r < 4; ++r) {
            size_t idx0 = (size_t)(tok_base + quad * 4 + r) * CDIM + d;
            size_t idx1 = (size_t)(tok_base + 16 + quad * 4 + r) * CDIM + d;
            out[idx0] = x[idx0] + acc0[r] + bb;
            out[idx1] = x[idx1] + acc1[r] + bb;
        }
    }
}

extern "C" void kernel_launch(void* const* d_in, const int* in_sizes, int n_in,
                              void* d_out, int out_size, void* d_ws, size_t ws_size,
                              hipStream_t stream) {
    const float* x     = (const float*)d_in[0];
    const float* gamma = (const float*)d_in[1];
    const float* beta  = (const float*)d_in[2];
    const float* wq    = (const float*)d_in[3];
    const float* bq    = (const float*)d_in[4];
    const float* wk    = (const float*)d_in[5];
    const float* bk    = (const float*)d_in[6];
    const float* wv    = (const float*)d_in[7];
    const float* bv    = (const float*)d_in[8];
    const float* wo    = (const float*)d_in[9];
    const float* bo    = (const float*)d_in[10];
    float* out = (float*)d_out;

    // workspace layout (bytes):
    //   h    @ 0          16,777,216   (LN output; reused for attn)
    //   q    @ 16,777,216 16,777,216
    //   k2   @ 33,554,432 17,301,504   (padded tiled K: 512 tiles x 64 x 264)
    //   vt2  @ 50,855,936 17,825,792   (padded tiled Vt: 512 tiles x 256 x 68)
    //   wt   @ 68,681,728    524,288   (4 transposed bf16 weight matrices)
    char* ws = (char*)d_ws;
    unsigned short* h_bf = (unsigned short*)(ws);
    unsigned short* q_bf = (unsigned short*)(ws + 16777216);
    unsigned short* k2   = (unsigned short*)(ws + 33554432);
    unsigned short* vt2  = (unsigned short*)(ws + 50855936);
    unsigned short* wt   = (unsigned short*)(ws + 68681728);
    unsigned short* attn = h_bf;   // h dead after qkv

    prep_kernel<<<TOK / 4 + 1024, 256, 0, stream>>>(x, gamma, beta, wq, wk, wv, wo, h_bf, wt);
    qkv_kernel<<<TOK / 64, 256, 0, stream>>>(h_bf, wt, bq, bk, bv, q_bf, k2, vt2);
    flash_kernel<<<(NTOK / BQ) * NB, 512, 0, stream>>>(q_bf, k2, vt2, attn);
    oproj_kernel<<<TOK / 64, 128, 0, stream>>>(attn, wt + 3 * (CDIM * CDIM), bo, x, out);
}

// Round 8
// 380.873 us; speedup vs baseline: 1.8724x; 1.8724x over previous
//
#include <hip/hip_runtime.h>
#include <stdint.h>

// Problem constants: B=8, H=W=64, C=256
#define NB    8
#define NTOK  4096          // H*W tokens per batch
#define TOK   32768         // NB*NTOK
#define CDIM  256
#define BQ    128           // queries per block (flash): 32 per wave-pair
#define BK    64            // keys per LDS tile (flash); split 32/32 across wave halves
#define NT    (NTOK / BK)   // 64 key tiles

#define KPITCH 264          // Ks row pitch in shorts (pad +8, baked into k2 global)
#define VPITCH 68           // Vs row pitch in shorts (pad +4, baked into vt2 global)
#define KTILE_SH (BK * KPITCH)     // 16896 shorts = 33792 B
#define VTILE_SH (CDIM * VPITCH)   // 17408 shorts = 34816 B
#define KCH   33
#define VCH   34
#define TOTCH (KCH + VCH)   // 67 1-KB DMA chunks per tile

typedef __attribute__((ext_vector_type(8))) short bf16x8;   // 8 bf16 = 4 VGPRs
typedef __attribute__((ext_vector_type(4))) float f32x4;    // MFMA C/D frag

#define SSCALE 0.09016844f   // C^-0.5 * log2(e) = 0.0625 * 1.442695

static __device__ __forceinline__ unsigned short f2bf(float f) {
    union { float f; unsigned u; } v; v.f = f;
    unsigned r = v.u + 0x7fffu + ((v.u >> 16) & 1u);   // RNE
    return (unsigned short)(r >> 16);
}

// async global->LDS DMA: 16 B/lane, LDS dest = uniform base + lane*16
static __device__ __forceinline__ void dma16(const unsigned short* g, unsigned short* l) {
    __builtin_amdgcn_global_load_lds(
        (const __attribute__((address_space(1))) unsigned int*)g,
        (__attribute__((address_space(3))) unsigned int*)l,
        16, 0, 0);
}

// ---------------- prep: LayerNorm (blocks 0..8191) + weight transpose -------
__global__ __launch_bounds__(256) void prep_kernel(
        const float* __restrict__ x,
        const float* __restrict__ gamma,
        const float* __restrict__ beta,
        const float* __restrict__ w0, const float* __restrict__ w1,
        const float* __restrict__ w2, const float* __restrict__ w3,
        unsigned short* __restrict__ h_bf,
        unsigned short* __restrict__ wt) {
    int bx = blockIdx.x;
    if (bx >= TOK / 4) {
        // weight transpose + bf16 cast: Wt[d][c] = W[c][d]
        int id = bx - TOK / 4;            // 0..1023
        int m = id >> 8, dd = id & 255;
        const float* src = (m == 0) ? w0 : (m == 1) ? w1 : (m == 2) ? w2 : w3;
        wt[m * (CDIM * CDIM) + dd * CDIM + threadIdx.x] = f2bf(src[threadIdx.x * CDIM + dd]);
        return;
    }
    int w = threadIdx.x >> 6;
    int lane = threadIdx.x & 63;
    int token = bx * 4 + w;
    const float4 xv = ((const float4*)(x + (size_t)token * CDIM))[lane];
    float s = xv.x + xv.y + xv.z + xv.w;
    #pragma unroll
    for (int off = 1; off < 64; off <<= 1) s += __shfl_xor(s, off, 64);
    float mean = s * (1.0f / 256.0f);
    float d0 = xv.x - mean, d1 = xv.y - mean, d2 = xv.z - mean, d3 = xv.w - mean;
    float ss = d0 * d0 + d1 * d1 + d2 * d2 + d3 * d3;
    #pragma unroll
    for (int off = 1; off < 64; off <<= 1) ss += __shfl_xor(ss, off, 64);
    float rstd = rsqrtf(ss * (1.0f / 256.0f) + 1e-5f);
    float4 g = ((const float4*)gamma)[lane];
    float4 b = ((const float4*)beta)[lane];
    ushort4 o;
    o.x = f2bf(d0 * rstd * g.x + b.x);
    o.y = f2bf(d1 * rstd * g.y + b.y);
    o.z = f2bf(d2 * rstd * g.z + b.z);
    o.w = f2bf(d3 * rstd * g.w + b.w);
    ((ushort4*)(h_bf + (size_t)token * CDIM))[lane] = o;
}

// ---------------- fused Q+K+V projection, column-split for occupancy --------
// grid (512, 2), 128 thr. Block (bx,gy) = key tile bx, output columns
// nt = gy*8 .. gy*8+7 of ALL THREE projections. Each wave holds 2 A-sets
// (32 tokens) so every weight B-frag feeds two MFMAs (round-6 reuse kept);
// 2048 waves total -> 2 waves/SIMD. h read twice (vs 3x in round 6).
// Q -> plain [t][d] scaled; K -> padded k2[tile][row][264];
// V -> half-height LDS transpose -> padded vt2[tile][d][68].
__global__ __launch_bounds__(128) void qkv_kernel(
        const unsigned short* __restrict__ h_bf,
        const unsigned short* __restrict__ wts,
        const float* __restrict__ bq,
        const float* __restrict__ bk,
        const float* __restrict__ bv,
        unsigned short* __restrict__ q_bf,
        unsigned short* __restrict__ k2,
        unsigned short* __restrict__ vt2) {
    __shared__ unsigned short VT[128][VPITCH];   // 17408 B (half tile: d in [gy*128, gy*128+128))
    int tid = threadIdx.x;
    int w = tid >> 6, lane = tid & 63, quad = lane >> 4, l16 = lane & 15;
    int blk = blockIdx.x;
    int gy = blockIdx.y;
    int nt0 = gy * 8;
    int tok_base = blk * 64 + w * 32;

    bf16x8 afr[2][8];
    #pragma unroll
    for (int s = 0; s < 2; ++s)
        #pragma unroll
        for (int kk = 0; kk < 8; ++kk)
            afr[s][kk] = *(const bf16x8*)(h_bf + (size_t)(tok_base + s * 16 + l16) * CDIM + kk * 32 + quad * 8);

    // ---- Q (pre-scaled by SSCALE)
    {
        const unsigned short* wq_t = wts;
        #pragma unroll
        for (int ntl = 0; ntl < 8; ++ntl) {
            int nt = nt0 + ntl;
            f32x4 acc0 = {0.f, 0.f, 0.f, 0.f};
            f32x4 acc1 = {0.f, 0.f, 0.f, 0.f};
            #pragma unroll
            for (int kk = 0; kk < 8; ++kk) {
                bf16x8 bfr = *(const bf16x8*)(wq_t + (size_t)(nt * 16 + l16) * CDIM + kk * 32 + quad * 8);
                acc0 = __builtin_amdgcn_mfma_f32_16x16x32_bf16(afr[0][kk], bfr, acc0, 0, 0, 0);
                acc1 = __builtin_amdgcn_mfma_f32_16x16x32_bf16(afr[1][kk], bfr, acc1, 0, 0, 0);
            }
            int d = nt * 16 + l16;
            float bb = bq[d];
            #pragma unroll
            for (int r = 0; r < 4; ++r) {
                q_bf[(size_t)(tok_base + quad * 4 + r) * CDIM + d]      = f2bf((acc0[r] + bb) * SSCALE);
                q_bf[(size_t)(tok_base + 16 + quad * 4 + r) * CDIM + d] = f2bf((acc1[r] + bb) * SSCALE);
            }
        }
    }
    // ---- K (into padded tile)
    {
        const unsigned short* wk_t = wts + CDIM * CDIM;
        unsigned short* kdst = k2 + (size_t)blk * KTILE_SH;
        int row0 = w * 32 + quad * 4;
        #pragma unroll
        for (int ntl = 0; ntl < 8; ++ntl) {
            int nt = nt0 + ntl;
            f32x4 acc0 = {0.f, 0.f, 0.f, 0.f};
            f32x4 acc1 = {0.f, 0.f, 0.f, 0.f};
            #pragma unroll
            for (int kk = 0; kk < 8; ++kk) {
                bf16x8 bfr = *(const bf16x8*)(wk_t + (size_t)(nt * 16 + l16) * CDIM + kk * 32 + quad * 8);
                acc0 = __builtin_amdgcn_mfma_f32_16x16x32_bf16(afr[0][kk], bfr, acc0, 0, 0, 0);
                acc1 = __builtin_amdgcn_mfma_f32_16x16x32_bf16(afr[1][kk], bfr, acc1, 0, 0, 0);
            }
            int d = nt * 16 + l16;
            float bb = bk[d];
            #pragma unroll
            for (int r = 0; r < 4; ++r) {
                kdst[(size_t)(row0 + r) * KPITCH + d]      = f2bf(acc0[r] + bb);
                kdst[(size_t)(row0 + 16 + r) * KPITCH + d] = f2bf(acc1[r] + bb);
            }
        }
    }
    // ---- V (transpose through half-height LDS into padded tile)
    {
        const unsigned short* wv_t = wts + 2 * CDIM * CDIM;
        int col0 = w * 32 + quad * 4;
        #pragma unroll
        for (int ntl = 0; ntl < 8; ++ntl) {
            int nt = nt0 + ntl;
            f32x4 acc0 = {0.f, 0.f, 0.f, 0.f};
            f32x4 acc1 = {0.f, 0.f, 0.f, 0.f};
            #pragma unroll
            for (int kk = 0; kk < 8; ++kk) {
                bf16x8 bfr = *(const bf16x8*)(wv_t + (size_t)(nt * 16 + l16) * CDIM + kk * 32 + quad * 8);
                acc0 = __builtin_amdgcn_mfma_f32_16x16x32_bf16(afr[0][kk], bfr, acc0, 0, 0, 0);
                acc1 = __builtin_amdgcn_mfma_f32_16x16x32_bf16(afr[1][kk], bfr, acc1, 0, 0, 0);
            }
            int d = nt * 16 + l16;
            float bb = bv[d];
            int dl = ntl * 16 + l16;          // local row (d - gy*128)
            #pragma unroll
            for (int r = 0; r < 4; ++r) {
                VT[dl][col0 + r]      = f2bf(acc0[r] + bb);
                VT[dl][col0 + 16 + r] = f2bf(acc1[r] + bb);
            }
        }
    }
    __syncthreads();
    // flat coalesced copy-out: 1088 uint4 over 128 threads
    const uint4* src = (const uint4*)(&VT[0][0]);
    uint4* dst = (uint4*)(vt2 + (size_t)blk * VTILE_SH + (size_t)gy * 128 * VPITCH);
    #pragma unroll
    for (int i = 0; i < 8; ++i)
        dst[i * 128 + tid] = src[i * 128 + tid];
    if (tid < 64) dst[1024 + tid] = src[1024 + tid];
}

// ---------------- Flash attention: key-split wave pairs, DMA double-buffer ---
// (round-6 body, byte-for-byte: VGPR 128, no spill, 197 us)
// 8 waves, 512 thr, BQ=128. Wave w owns q-rows (w&3)*32..+32 and key half
// (w>>2) of each 64-key tile: every K/V LDS frag feeds TWO MFMAs (2 q-rowsets).
// Wave pairs (w, w+4) hold partial O/l over disjoint key halves; combined in
// the epilogue through the dead K/V LDS buffers. No-max softmax; P stored by
// bf16 truncation.
#define DMA_TILE(KS, VS, ktn)                                                        \
    {                                                                                \
        const unsigned short* gk = k2 + (size_t)(b * NT + (ktn)) * KTILE_SH;         \
        const unsigned short* gv = vt2 + (size_t)(b * NT + (ktn)) * VTILE_SH;        \
        for (int c = w; c < TOTCH; c += 8) {                                         \
            if (c < KCH) dma16(gk + c * 512 + lane * 8, &KS[0][0] + c * 512);        \
            else dma16(gv + (c - KCH) * 512 + lane * 8, &VS[0][0] + (c - KCH) * 512);\
        }                                                                            \
    }

#define COMPUTE_TILE(KS, VS)                                                         \
    {                                                                                \
        f32x4 sfr[2][2];                                                             \
        _Pragma("unroll")                                                            \
        for (int nt = 0; nt < 2; ++nt) {                                             \
            f32x4 a0 = {0.f, 0.f, 0.f, 0.f};                                         \
            f32x4 a1 = {0.f, 0.f, 0.f, 0.f};                                         \
            _Pragma("unroll")                                                        \
            for (int kk = 0; kk < 8; ++kk) {                                         \
                bf16x8 kb = *(const bf16x8*)(&KS[kh * 32 + nt * 16 + l16][kk * 32 + quad * 8]); \
                a0 = __builtin_amdgcn_mfma_f32_16x16x32_bf16(qfr[0][kk], kb, a0, 0, 0, 0);      \
                a1 = __builtin_amdgcn_mfma_f32_16x16x32_bf16(qfr[1][kk], kb, a1, 0, 0, 0);      \
            }                                                                        \
            sfr[0][nt] = a0; sfr[1][nt] = a1;                                        \
        }                                                                            \
        _Pragma("unroll")                                                            \
        for (int s = 0; s < 2; ++s)                                                  \
            _Pragma("unroll")                                                        \
            for (int nt = 0; nt < 2; ++nt)                                           \
                _Pragma("unroll")                                                    \
                for (int r = 0; r < 4; ++r) {                                        \
                    float p = exp2f(sfr[s][nt][r]);                                  \
                    lacc[s][r] += p;                                                 \
                    Pl[wq * 32 + s * 16 + quad * 4 + r][kh * 32 + nt * 16 + l16] =   \
                        (unsigned short)(__float_as_uint(p) >> 16);                  \
                }                                                                    \
        bf16x8 pfr0 = *(const bf16x8*)(&Pl[wq * 32 + l16][kh * 32 + quad * 8]);      \
        bf16x8 pfr1 = *(const bf16x8*)(&Pl[wq * 32 + 16 + l16][kh * 32 + quad * 8]); \
        _Pragma("unroll")                                                            \
        for (int nt2 = 0; nt2 < 16; ++nt2) {                                         \
            bf16x8 vb = *(const bf16x8*)(&VS[nt2 * 16 + l16][kh * 32 + quad * 8]);   \
            O[0][nt2] = __builtin_amdgcn_mfma_f32_16x16x32_bf16(pfr0, vb, O[0][nt2], 0, 0, 0);  \
            O[1][nt2] = __builtin_amdgcn_mfma_f32_16x16x32_bf16(pfr1, vb, O[1][nt2], 0, 0, 0);  \
        }                                                                            \
    }

__global__ __launch_bounds__(512, 2) void flash_kernel(
        const unsigned short* __restrict__ q_bf,
        const unsigned short* __restrict__ k2,
        const unsigned short* __restrict__ vt2,
        unsigned short* __restrict__ attn) {
    __shared__ unsigned short Ks0[BK][KPITCH];    // 33792 B
    __shared__ unsigned short Ks1[BK][KPITCH];    // 33792 B
    __shared__ unsigned short Vs0[CDIM][VPITCH];  // 34816 B
    __shared__ unsigned short Vs1[CDIM][VPITCH];  // 34816 B
    __shared__ unsigned short Pl[BQ][VPITCH];     // 17408 B  (total 154.6 KB)

    int tid = threadIdx.x;
    int w = tid >> 6, lane = tid & 63, quad = lane >> 4, l16 = lane & 15;
    int kh = w >> 2;        // key half of each tile
    int wq = w & 3;         // q-row group (shared with wave w^4)
    int bid = blockIdx.x;
    int b = bid & 7;        // XCD swizzle: same batch -> same XCD L2
    int qtile = bid >> 3;
    int qrow = qtile * BQ + wq * 32;
    const size_t bbase = (size_t)b * NTOK * CDIM;

    bf16x8 qfr[2][8];
    #pragma unroll
    for (int s = 0; s < 2; ++s)
        #pragma unroll
        for (int kk = 0; kk < 8; ++kk)
            qfr[s][kk] = *(const bf16x8*)(q_bf + bbase + (size_t)(qrow + s * 16 + l16) * CDIM + kk * 32 + quad * 8);

    f32x4 O[2][16];
    #pragma unroll
    for (int s = 0; s < 2; ++s)
        #pragma unroll
        for (int i = 0; i < 16; ++i) O[s][i] = (f32x4){0.f, 0.f, 0.f, 0.f};
    float lacc[2][4] = {{0.f, 0.f, 0.f, 0.f}, {0.f, 0.f, 0.f, 0.f}};

    DMA_TILE(Ks0, Vs0, 0);
    __syncthreads();

    for (int kt2 = 0; kt2 < NT; kt2 += 2) {
        DMA_TILE(Ks1, Vs1, kt2 + 1);
        COMPUTE_TILE(Ks0, Vs0);
        __syncthreads();
        if (kt2 + 2 < NT) DMA_TILE(Ks0, Vs0, kt2 + 2);
        COMPUTE_TILE(Ks1, Vs1);
        __syncthreads();
    }

    // ---- epilogue: combine wave pairs (key halves) through dead LDS buffers
    float* sO = (wq == 0) ? (float*)&Ks0[0][0] : (wq == 1) ? (float*)&Ks1[0][0]
              : (wq == 2) ? (float*)&Vs0[0][0] : (float*)&Vs1[0][0];
    float* sL = (float*)&Pl[0][0] + wq * 512;    // 2*4*64 floats per pair

    if (kh == 1) {
        #pragma unroll
        for (int s = 0; s < 2; ++s) {
            #pragma unroll
            for (int nt2 = 0; nt2 < 16; ++nt2)
                #pragma unroll
                for (int r = 0; r < 4; ++r)
                    sO[((s * 16 + nt2) * 4 + r) * 64 + lane] = O[s][nt2][r];
            #pragma unroll
            for (int r = 0; r < 4; ++r)
                sL[(s * 4 + r) * 64 + lane] = lacc[s][r];
        }
    }
    __syncthreads();
    if (kh == 0) {
        float linv[2][4];
        #pragma unroll
        for (int s = 0; s < 2; ++s)
            #pragma unroll
            for (int r = 0; r < 4; ++r) {
                float ls = lacc[s][r] + sL[(s * 4 + r) * 64 + lane];
                #pragma unroll
                for (int off = 1; off < 16; off <<= 1)
                    ls += __shfl_xor(ls, off, 64);
                linv[s][r] = 1.0f / ls;
            }
        #pragma unroll
        for (int s = 0; s < 2; ++s)
            #pragma unroll
            for (int nt2 = 0; nt2 < 16; ++nt2) {
                int d = nt2 * 16 + l16;
                #pragma unroll
                for (int r = 0; r < 4; ++r) {
                    float val = (O[s][nt2][r] + sO[((s * 16 + nt2) * 4 + r) * 64 + lane]) * linv[s][r];
                    attn[bbase + (size_t)(qrow + s * 16 + quad * 4 + r) * CDIM + d] = f2bf(val);
                }
            }
    }
}

// ---------------- output projection + bias + residual, fp32 out -------------
__global__ __launch_bounds__(128) void oproj_kernel(
        const unsigned short* __restrict__ attn,
        const unsigned short* __restrict__ wo_t,
        const float* __restrict__ bo,
        const float* __restrict__ x,
        float* __restrict__ out) {
    int w = threadIdx.x >> 6, lane = threadIdx.x & 63;
    int quad = lane >> 4, l16 = lane & 15;
    int tok_base = blockIdx.x * 64 + w * 32;

    bf16x8 afr[2][8];
    #pragma unroll
    for (int s = 0; s < 2; ++s)
        #pragma unroll
        for (int kk = 0; kk < 8; ++kk)
            afr[s][kk] = *(const bf16x8*)(attn + (size_t)(tok_base + s * 16 + l16) * CDIM + kk * 32 + quad * 8);

    #pragma unroll
    for (int nt = 0; nt < 16; ++nt) {
        f32x4 acc0 = {0.f, 0.f, 0.f, 0.f};
        f32x4 acc1 = {0.f, 0.f, 0.f, 0.f};
        #pragma unroll
        for (int kk = 0; kk < 8; ++kk) {
            bf16x8 bfr = *(const bf16x8*)(wo_t + (size_t)(nt * 16 + l16) * CDIM + kk * 32 + quad * 8);
            acc0 = __builtin_amdgcn_mfma_f32_16x16x32_bf16(afr[0][kk], bfr, acc0, 0, 0, 0);
            acc1 = __builtin_amdgcn_mfma_f32_16x16x32_bf16(afr[1][kk], bfr, acc1, 0, 0, 0);
        }
        int d = nt * 16 + l16;
        float bb = bo[d];
        #pragma unroll
        for (int r = 0; r < 4; ++r) {
            size_t idx0 = (size_t)(tok_base + quad * 4 + r) * CDIM + d;
            size_t idx1 = (size_t)(tok_base + 16 + quad * 4 + r) * CDIM + d;
            out[idx0] = x[idx0] + acc0[r] + bb;
            out[idx1] = x[idx1] + acc1[r] + bb;
        }
    }
}

extern "C" void kernel_launch(void* const* d_in, const int* in_sizes, int n_in,
                              void* d_out, int out_size, void* d_ws, size_t ws_size,
                              hipStream_t stream) {
    const float* x     = (const float*)d_in[0];
    const float* gamma = (const float*)d_in[1];
    const float* beta  = (const float*)d_in[2];
    const float* wq    = (const float*)d_in[3];
    const float* bq    = (const float*)d_in[4];
    const float* wk    = (const float*)d_in[5];
    const float* bk    = (const float*)d_in[6];
    const float* wv    = (const float*)d_in[7];
    const float* bv    = (const float*)d_in[8];
    const float* wo    = (const float*)d_in[9];
    const float* bo    = (const float*)d_in[10];
    float* out = (float*)d_out;

    // workspace layout (bytes):
    //   h    @ 0          16,777,216   (LN output; reused for attn)
    //   q    @ 16,777,216 16,777,216
    //   k2   @ 33,554,432 17,301,504   (padded tiled K: 512 tiles x 64 x 264)
    //   vt2  @ 50,855,936 17,825,792   (padded tiled Vt: 512 tiles x 256 x 68)
    //   wt   @ 68,681,728    524,288   (4 transposed bf16 weight matrices)
    char* ws = (char*)d_ws;
    unsigned short* h_bf = (unsigned short*)(ws);
    unsigned short* q_bf = (unsigned short*)(ws + 16777216);
    unsigned short* k2   = (unsigned short*)(ws + 33554432);
    unsigned short* vt2  = (unsigned short*)(ws + 50855936);
    unsigned short* wt   = (unsigned short*)(ws + 68681728);
    unsigned short* attn = h_bf;   // h dead after qkv

    prep_kernel<<<TOK / 4 + 1024, 256, 0, stream>>>(x, gamma, beta, wq, wk, wv, wo, h_bf, wt);
    qkv_kernel<<<dim3(TOK / 64, 2), 128, 0, stream>>>(h_bf, wt, bq, bk, bv, q_bf, k2, vt2);
    flash_kernel<<<(NTOK / BQ) * NB, 512, 0, stream>>>(q_bf, k2, vt2, attn);
    oproj_kernel<<<TOK / 64, 128, 0, stream>>>(attn, wt + 3 * (CDIM * CDIM), bo, x, out);
}

// Round 9
// 360.727 us; speedup vs baseline: 1.9770x; 1.0558x over previous
//
#include <hip/hip_runtime.h>
#include <stdint.h>

// Problem constants: B=8, H=W=64, C=256
#define NB    8
#define NTOK  4096          // H*W tokens per batch
#define TOK   32768         // NB*NTOK
#define CDIM  256
#define BQ    128           // queries per block (flash): 32 per wave-pair
#define BK    64            // keys per LDS tile (flash); split 32/32 across wave halves
#define NT    (NTOK / BK)   // 64 key tiles

#define KPITCH 264          // Ks row pitch in shorts (pad +8, baked into k2 global)
#define VPITCH 68           // Vs row pitch in shorts (pad +4, baked into vt2 global)
#define KTILE_SH (BK * KPITCH)     // 16896 shorts = 33792 B
#define VTILE_SH (CDIM * VPITCH)   // 17408 shorts = 34816 B
#define KCH   33
#define VCH   34
#define TOTCH (KCH + VCH)   // 67 1-KB DMA chunks per tile

typedef __attribute__((ext_vector_type(8))) short bf16x8;   // 8 bf16 = 4 VGPRs
typedef __attribute__((ext_vector_type(4))) float f32x4;    // MFMA C/D frag

#define SSCALE 0.09016844f   // C^-0.5 * log2(e) = 0.0625 * 1.442695

static __device__ __forceinline__ unsigned short f2bf(float f) {
    union { float f; unsigned u; } v; v.f = f;
    unsigned r = v.u + 0x7fffu + ((v.u >> 16) & 1u);   // RNE
    return (unsigned short)(r >> 16);
}

// async global->LDS DMA: 16 B/lane, LDS dest = uniform base + lane*16
static __device__ __forceinline__ void dma16(const unsigned short* g, unsigned short* l) {
    __builtin_amdgcn_global_load_lds(
        (const __attribute__((address_space(1))) unsigned int*)g,
        (__attribute__((address_space(3))) unsigned int*)l,
        16, 0, 0);
}

// ---------------- prep: LayerNorm (blocks 0..8191) + weight transpose -------
__global__ __launch_bounds__(256) void prep_kernel(
        const float* __restrict__ x,
        const float* __restrict__ gamma,
        const float* __restrict__ beta,
        const float* __restrict__ w0, const float* __restrict__ w1,
        const float* __restrict__ w2, const float* __restrict__ w3,
        unsigned short* __restrict__ h_bf,
        unsigned short* __restrict__ wt) {
    int bx = blockIdx.x;
    if (bx >= TOK / 4) {
        // weight transpose + bf16 cast: Wt[d][c] = W[c][d]
        int id = bx - TOK / 4;            // 0..1023
        int m = id >> 8, dd = id & 255;
        const float* src = (m == 0) ? w0 : (m == 1) ? w1 : (m == 2) ? w2 : w3;
        wt[m * (CDIM * CDIM) + dd * CDIM + threadIdx.x] = f2bf(src[threadIdx.x * CDIM + dd]);
        return;
    }
    int w = threadIdx.x >> 6;
    int lane = threadIdx.x & 63;
    int token = bx * 4 + w;
    const float4 xv = ((const float4*)(x + (size_t)token * CDIM))[lane];
    float s = xv.x + xv.y + xv.z + xv.w;
    #pragma unroll
    for (int off = 1; off < 64; off <<= 1) s += __shfl_xor(s, off, 64);
    float mean = s * (1.0f / 256.0f);
    float d0 = xv.x - mean, d1 = xv.y - mean, d2 = xv.z - mean, d3 = xv.w - mean;
    float ss = d0 * d0 + d1 * d1 + d2 * d2 + d3 * d3;
    #pragma unroll
    for (int off = 1; off < 64; off <<= 1) ss += __shfl_xor(ss, off, 64);
    float rstd = rsqrtf(ss * (1.0f / 256.0f) + 1e-5f);
    float4 g = ((const float4*)gamma)[lane];
    float4 b = ((const float4*)beta)[lane];
    ushort4 o;
    o.x = f2bf(d0 * rstd * g.x + b.x);
    o.y = f2bf(d1 * rstd * g.y + b.y);
    o.z = f2bf(d2 * rstd * g.z + b.z);
    o.w = f2bf(d3 * rstd * g.w + b.w);
    ((ushort4*)(h_bf + (size_t)token * CDIM))[lane] = o;
}

// ---------------- fused Q+K+V projection, 4-way column-split ----------------
// grid (512, 4), 128 thr. Block (bx,gy) = key tile bx, output columns
// nt = gy*4 .. gy*4+3 of ALL THREE projections. Each wave holds 2 A-sets
// (32 tokens) so every weight B-frag feeds two MFMAs. 4096 waves total ->
// 4 waves/SIMD (the round-8 shape gave only 2 -> latency-stall bound).
// Weight traffic is NOT duplicated by the split (disjoint nt ranges);
// only h A-frags re-read (x4, bf16, cheap).
__global__ __launch_bounds__(128) void qkv_kernel(
        const unsigned short* __restrict__ h_bf,
        const unsigned short* __restrict__ wts,
        const float* __restrict__ bq,
        const float* __restrict__ bk,
        const float* __restrict__ bv,
        unsigned short* __restrict__ q_bf,
        unsigned short* __restrict__ k2,
        unsigned short* __restrict__ vt2) {
    __shared__ unsigned short VT[64][VPITCH];   // 8704 B (quarter tile: d in [gy*64, gy*64+64))
    int tid = threadIdx.x;
    int w = tid >> 6, lane = tid & 63, quad = lane >> 4, l16 = lane & 15;
    int blk = blockIdx.x;
    int gy = blockIdx.y;
    int nt0 = gy * 4;
    int tok_base = blk * 64 + w * 32;

    bf16x8 afr[2][8];
    #pragma unroll
    for (int s = 0; s < 2; ++s)
        #pragma unroll
        for (int kk = 0; kk < 8; ++kk)
            afr[s][kk] = *(const bf16x8*)(h_bf + (size_t)(tok_base + s * 16 + l16) * CDIM + kk * 32 + quad * 8);

    // ---- Q (pre-scaled by SSCALE)
    {
        const unsigned short* wq_t = wts;
        #pragma unroll
        for (int ntl = 0; ntl < 4; ++ntl) {
            int nt = nt0 + ntl;
            f32x4 acc0 = {0.f, 0.f, 0.f, 0.f};
            f32x4 acc1 = {0.f, 0.f, 0.f, 0.f};
            #pragma unroll
            for (int kk = 0; kk < 8; ++kk) {
                bf16x8 bfr = *(const bf16x8*)(wq_t + (size_t)(nt * 16 + l16) * CDIM + kk * 32 + quad * 8);
                acc0 = __builtin_amdgcn_mfma_f32_16x16x32_bf16(afr[0][kk], bfr, acc0, 0, 0, 0);
                acc1 = __builtin_amdgcn_mfma_f32_16x16x32_bf16(afr[1][kk], bfr, acc1, 0, 0, 0);
            }
            int d = nt * 16 + l16;
            float bb = bq[d];
            #pragma unroll
            for (int r = 0; r < 4; ++r) {
                q_bf[(size_t)(tok_base + quad * 4 + r) * CDIM + d]      = f2bf((acc0[r] + bb) * SSCALE);
                q_bf[(size_t)(tok_base + 16 + quad * 4 + r) * CDIM + d] = f2bf((acc1[r] + bb) * SSCALE);
            }
        }
    }
    // ---- K (into padded tile)
    {
        const unsigned short* wk_t = wts + CDIM * CDIM;
        unsigned short* kdst = k2 + (size_t)blk * KTILE_SH;
        int row0 = w * 32 + quad * 4;
        #pragma unroll
        for (int ntl = 0; ntl < 4; ++ntl) {
            int nt = nt0 + ntl;
            f32x4 acc0 = {0.f, 0.f, 0.f, 0.f};
            f32x4 acc1 = {0.f, 0.f, 0.f, 0.f};
            #pragma unroll
            for (int kk = 0; kk < 8; ++kk) {
                bf16x8 bfr = *(const bf16x8*)(wk_t + (size_t)(nt * 16 + l16) * CDIM + kk * 32 + quad * 8);
                acc0 = __builtin_amdgcn_mfma_f32_16x16x32_bf16(afr[0][kk], bfr, acc0, 0, 0, 0);
                acc1 = __builtin_amdgcn_mfma_f32_16x16x32_bf16(afr[1][kk], bfr, acc1, 0, 0, 0);
            }
            int d = nt * 16 + l16;
            float bb = bk[d];
            #pragma unroll
            for (int r = 0; r < 4; ++r) {
                kdst[(size_t)(row0 + r) * KPITCH + d]      = f2bf(acc0[r] + bb);
                kdst[(size_t)(row0 + 16 + r) * KPITCH + d] = f2bf(acc1[r] + bb);
            }
        }
    }
    // ---- V (transpose through quarter-height LDS into padded tile)
    {
        const unsigned short* wv_t = wts + 2 * CDIM * CDIM;
        int col0 = w * 32 + quad * 4;
        #pragma unroll
        for (int ntl = 0; ntl < 4; ++ntl) {
            int nt = nt0 + ntl;
            f32x4 acc0 = {0.f, 0.f, 0.f, 0.f};
            f32x4 acc1 = {0.f, 0.f, 0.f, 0.f};
            #pragma unroll
            for (int kk = 0; kk < 8; ++kk) {
                bf16x8 bfr = *(const bf16x8*)(wv_t + (size_t)(nt * 16 + l16) * CDIM + kk * 32 + quad * 8);
                acc0 = __builtin_amdgcn_mfma_f32_16x16x32_bf16(afr[0][kk], bfr, acc0, 0, 0, 0);
                acc1 = __builtin_amdgcn_mfma_f32_16x16x32_bf16(afr[1][kk], bfr, acc1, 0, 0, 0);
            }
            int d = nt * 16 + l16;
            float bb = bv[d];
            int dl = ntl * 16 + l16;          // local row (d - gy*64)
            #pragma unroll
            for (int r = 0; r < 4; ++r) {
                VT[dl][col0 + r]      = f2bf(acc0[r] + bb);
                VT[dl][col0 + 16 + r] = f2bf(acc1[r] + bb);
            }
        }
    }
    __syncthreads();
    // flat coalesced copy-out: 544 uint4 over 128 threads
    const uint4* src = (const uint4*)(&VT[0][0]);
    uint4* dst = (uint4*)(vt2 + (size_t)blk * VTILE_SH + (size_t)gy * 64 * VPITCH);
    #pragma unroll
    for (int i = 0; i < 4; ++i)
        dst[i * 128 + tid] = src[i * 128 + tid];
    if (tid < 32) dst[512 + tid] = src[512 + tid];
}

// ---------------- Flash attention: key-split wave pairs, DMA double-buffer ---
// (round-6 body, byte-for-byte: VGPR 128, no spill, 197 us)
// 8 waves, 512 thr, BQ=128. Wave w owns q-rows (w&3)*32..+32 and key half
// (w>>2) of each 64-key tile: every K/V LDS frag feeds TWO MFMAs (2 q-rowsets).
// Wave pairs (w, w+4) hold partial O/l over disjoint key halves; combined in
// the epilogue through the dead K/V LDS buffers. No-max softmax; P stored by
// bf16 truncation.
#define DMA_TILE(KS, VS, ktn)                                                        \
    {                                                                                \
        const unsigned short* gk = k2 + (size_t)(b * NT + (ktn)) * KTILE_SH;         \
        const unsigned short* gv = vt2 + (size_t)(b * NT + (ktn)) * VTILE_SH;        \
        for (int c = w; c < TOTCH; c += 8) {                                         \
            if (c < KCH) dma16(gk + c * 512 + lane * 8, &KS[0][0] + c * 512);        \
            else dma16(gv + (c - KCH) * 512 + lane * 8, &VS[0][0] + (c - KCH) * 512);\
        }                                                                            \
    }

#define COMPUTE_TILE(KS, VS)                                                         \
    {                                                                                \
        f32x4 sfr[2][2];                                                             \
        _Pragma("unroll")                                                            \
        for (int nt = 0; nt < 2; ++nt) {                                             \
            f32x4 a0 = {0.f, 0.f, 0.f, 0.f};                                         \
            f32x4 a1 = {0.f, 0.f, 0.f, 0.f};                                         \
            _Pragma("unroll")                                                        \
            for (int kk = 0; kk < 8; ++kk) {                                         \
                bf16x8 kb = *(const bf16x8*)(&KS[kh * 32 + nt * 16 + l16][kk * 32 + quad * 8]); \
                a0 = __builtin_amdgcn_mfma_f32_16x16x32_bf16(qfr[0][kk], kb, a0, 0, 0, 0);      \
                a1 = __builtin_amdgcn_mfma_f32_16x16x32_bf16(qfr[1][kk], kb, a1, 0, 0, 0);      \
            }                                                                        \
            sfr[0][nt] = a0; sfr[1][nt] = a1;                                        \
        }                                                                            \
        _Pragma("unroll")                                                            \
        for (int s = 0; s < 2; ++s)                                                  \
            _Pragma("unroll")                                                        \
            for (int nt = 0; nt < 2; ++nt)                                           \
                _Pragma("unroll")                                                    \
                for (int r = 0; r < 4; ++r) {                                        \
                    float p = exp2f(sfr[s][nt][r]);                                  \
                    lacc[s][r] += p;                                                 \
                    Pl[wq * 32 + s * 16 + quad * 4 + r][kh * 32 + nt * 16 + l16] =   \
                        (unsigned short)(__float_as_uint(p) >> 16);                  \
                }                                                                    \
        bf16x8 pfr0 = *(const bf16x8*)(&Pl[wq * 32 + l16][kh * 32 + quad * 8]);      \
        bf16x8 pfr1 = *(const bf16x8*)(&Pl[wq * 32 + 16 + l16][kh * 32 + quad * 8]); \
        _Pragma("unroll")                                                            \
        for (int nt2 = 0; nt2 < 16; ++nt2) {                                         \
            bf16x8 vb = *(const bf16x8*)(&VS[nt2 * 16 + l16][kh * 32 + quad * 8]);   \
            O[0][nt2] = __builtin_amdgcn_mfma_f32_16x16x32_bf16(pfr0, vb, O[0][nt2], 0, 0, 0);  \
            O[1][nt2] = __builtin_amdgcn_mfma_f32_16x16x32_bf16(pfr1, vb, O[1][nt2], 0, 0, 0);  \
        }                                                                            \
    }

__global__ __launch_bounds__(512, 2) void flash_kernel(
        const unsigned short* __restrict__ q_bf,
        const unsigned short* __restrict__ k2,
        const unsigned short* __restrict__ vt2,
        unsigned short* __restrict__ attn) {
    __shared__ unsigned short Ks0[BK][KPITCH];    // 33792 B
    __shared__ unsigned short Ks1[BK][KPITCH];    // 33792 B
    __shared__ unsigned short Vs0[CDIM][VPITCH];  // 34816 B
    __shared__ unsigned short Vs1[CDIM][VPITCH];  // 34816 B
    __shared__ unsigned short Pl[BQ][VPITCH];     // 17408 B  (total 154.6 KB)

    int tid = threadIdx.x;
    int w = tid >> 6, lane = tid & 63, quad = lane >> 4, l16 = lane & 15;
    int kh = w >> 2;        // key half of each tile
    int wq = w & 3;         // q-row group (shared with wave w^4)
    int bid = blockIdx.x;
    int b = bid & 7;        // XCD swizzle: same batch -> same XCD L2
    int qtile = bid >> 3;
    int qrow = qtile * BQ + wq * 32;
    const size_t bbase = (size_t)b * NTOK * CDIM;

    bf16x8 qfr[2][8];
    #pragma unroll
    for (int s = 0; s < 2; ++s)
        #pragma unroll
        for (int kk = 0; kk < 8; ++kk)
            qfr[s][kk] = *(const bf16x8*)(q_bf + bbase + (size_t)(qrow + s * 16 + l16) * CDIM + kk * 32 + quad * 8);

    f32x4 O[2][16];
    #pragma unroll
    for (int s = 0; s < 2; ++s)
        #pragma unroll
        for (int i = 0; i < 16; ++i) O[s][i] = (f32x4){0.f, 0.f, 0.f, 0.f};
    float lacc[2][4] = {{0.f, 0.f, 0.f, 0.f}, {0.f, 0.f, 0.f, 0.f}};

    DMA_TILE(Ks0, Vs0, 0);
    __syncthreads();

    for (int kt2 = 0; kt2 < NT; kt2 += 2) {
        DMA_TILE(Ks1, Vs1, kt2 + 1);
        COMPUTE_TILE(Ks0, Vs0);
        __syncthreads();
        if (kt2 + 2 < NT) DMA_TILE(Ks0, Vs0, kt2 + 2);
        COMPUTE_TILE(Ks1, Vs1);
        __syncthreads();
    }

    // ---- epilogue: combine wave pairs (key halves) through dead LDS buffers
    float* sO = (wq == 0) ? (float*)&Ks0[0][0] : (wq == 1) ? (float*)&Ks1[0][0]
              : (wq == 2) ? (float*)&Vs0[0][0] : (float*)&Vs1[0][0];
    float* sL = (float*)&Pl[0][0] + wq * 512;    // 2*4*64 floats per pair

    if (kh == 1) {
        #pragma unroll
        for (int s = 0; s < 2; ++s) {
            #pragma unroll
            for (int nt2 = 0; nt2 < 16; ++nt2)
                #pragma unroll
                for (int r = 0; r < 4; ++r)
                    sO[((s * 16 + nt2) * 4 + r) * 64 + lane] = O[s][nt2][r];
            #pragma unroll
            for (int r = 0; r < 4; ++r)
                sL[(s * 4 + r) * 64 + lane] = lacc[s][r];
        }
    }
    __syncthreads();
    if (kh == 0) {
        float linv[2][4];
        #pragma unroll
        for (int s = 0; s < 2; ++s)
            #pragma unroll
            for (int r = 0; r < 4; ++r) {
                float ls = lacc[s][r] + sL[(s * 4 + r) * 64 + lane];
                #pragma unroll
                for (int off = 1; off < 16; off <<= 1)
                    ls += __shfl_xor(ls, off, 64);
                linv[s][r] = 1.0f / ls;
            }
        #pragma unroll
        for (int s = 0; s < 2; ++s)
            #pragma unroll
            for (int nt2 = 0; nt2 < 16; ++nt2) {
                int d = nt2 * 16 + l16;
                #pragma unroll
                for (int r = 0; r < 4; ++r) {
                    float val = (O[s][nt2][r] + sO[((s * 16 + nt2) * 4 + r) * 64 + lane]) * linv[s][r];
                    attn[bbase + (size_t)(qrow + s * 16 + quad * 4 + r) * CDIM + d] = f2bf(val);
                }
            }
    }
}

// ---------------- output projection + bias + residual, 2-way column-split ---
// grid (512, 2), 128 thr: 2048 waves (round-8 shape had 1024 -> 1 wave/SIMD,
// 25% device fill). Block (bx,gy) computes output columns nt = gy*8..gy*8+7;
// x/out/weight traffic disjoint across gy (no duplication), attn re-read x2.
__global__ __launch_bounds__(128) void oproj_kernel(
        const unsigned short* __restrict__ attn,
        const unsigned short* __restrict__ wo_t,
        const float* __restrict__ bo,
        const float* __restrict__ x,
        float* __restrict__ out) {
    int w = threadIdx.x >> 6, lane = threadIdx.x & 63;
    int quad = lane >> 4, l16 = lane & 15;
    int tok_base = blockIdx.x * 64 + w * 32;
    int nt0 = blockIdx.y * 8;

    bf16x8 afr[2][8];
    #pragma unroll
    for (int s = 0; s < 2; ++s)
        #pragma unroll
        for (int kk = 0; kk < 8; ++kk)
            afr[s][kk] = *(const bf16x8*)(attn + (size_t)(tok_base + s * 16 + l16) * CDIM + kk * 32 + quad * 8);

    #pragma unroll
    for (int ntl = 0; ntl < 8; ++ntl) {
        int nt = nt0 + ntl;
        f32x4 acc0 = {0.f, 0.f, 0.f, 0.f};
        f32x4 acc1 = {0.f, 0.f, 0.f, 0.f};
        #pragma unroll
        for (int kk = 0; kk < 8; ++kk) {
            bf16x8 bfr = *(const bf16x8*)(wo_t + (size_t)(nt * 16 + l16) * CDIM + kk * 32 + quad * 8);
            acc0 = __builtin_amdgcn_mfma_f32_16x16x32_bf16(afr[0][kk], bfr, acc0, 0, 0, 0);
            acc1 = __builtin_amdgcn_mfma_f32_16x16x32_bf16(afr[1][kk], bfr, acc1, 0, 0, 0);
        }
        int d = nt * 16 + l16;
        float bb = bo[d];
        #pragma unroll
        for (int r = 0; r < 4; ++r) {
            size_t idx0 = (size_t)(tok_base + quad * 4 + r) * CDIM + d;
            size_t idx1 = (size_t)(tok_base + 16 + quad * 4 + r) * CDIM + d;
            out[idx0] = x[idx0] + acc0[r] + bb;
            out[idx1] = x[idx1] + acc1[r] + bb;
        }
    }
}

extern "C" void kernel_launch(void* const* d_in, const int* in_sizes, int n_in,
                              void* d_out, int out_size, void* d_ws, size_t ws_size,
                              hipStream_t stream) {
    const float* x     = (const float*)d_in[0];
    const float* gamma = (const float*)d_in[1];
    const float* beta  = (const float*)d_in[2];
    const float* wq    = (const float*)d_in[3];
    const float* bq    = (const float*)d_in[4];
    const float* wk    = (const float*)d_in[5];
    const float* bk    = (const float*)d_in[6];
    const float* wv    = (const float*)d_in[7];
    const float* bv    = (const float*)d_in[8];
    const float* wo    = (const float*)d_in[9];
    const float* bo    = (const float*)d_in[10];
    float* out = (float*)d_out;

    // workspace layout (bytes):
    //   h    @ 0          16,777,216   (LN output; reused for attn)
    //   q    @ 16,777,216 16,777,216
    //   k2   @ 33,554,432 17,301,504   (padded tiled K: 512 tiles x 64 x 264)
    //   vt2  @ 50,855,936 17,825,792   (padded tiled Vt: 512 tiles x 256 x 68)
    //   wt   @ 68,681,728    524,288   (4 transposed bf16 weight matrices)
    char* ws = (char*)d_ws;
    unsigned short* h_bf = (unsigned short*)(ws);
    unsigned short* q_bf = (unsigned short*)(ws + 16777216);
    unsigned short* k2   = (unsigned short*)(ws + 33554432);
    unsigned short* vt2  = (unsigned short*)(ws + 50855936);
    unsigned short* wt   = (unsigned short*)(ws + 68681728);
    unsigned short* attn = h_bf;   // h dead after qkv

    prep_kernel<<<TOK / 4 + 1024, 256, 0, stream>>>(x, gamma, beta, wq, wk, wv, wo, h_bf, wt);
    qkv_kernel<<<dim3(TOK / 64, 4), 128, 0, stream>>>(h_bf, wt, bq, bk, bv, q_bf, k2, vt2);
    flash_kernel<<<(NTOK / BQ) * NB, 512, 0, stream>>>(q_bf, k2, vt2, attn);
    oproj_kernel<<<dim3(TOK / 64, 2), 128, 0, stream>>>(attn, wt + 3 * (CDIM * CDIM), bo, x, out);
}